// Round 1
// baseline (1990.760 us; speedup 1.0000x reference)
//
#include <hip/hip_runtime.h>
#include <math.h>

#define Nn 16384
#define Fd 64
#define Hd 128
#define Kk 32

#define FMA16(acc, qv, pv) \
  acc[0][0]=fmaf(qv.x,pv.x,acc[0][0]); acc[0][1]=fmaf(qv.x,pv.y,acc[0][1]); \
  acc[0][2]=fmaf(qv.x,pv.z,acc[0][2]); acc[0][3]=fmaf(qv.x,pv.w,acc[0][3]); \
  acc[1][0]=fmaf(qv.y,pv.x,acc[1][0]); acc[1][1]=fmaf(qv.y,pv.y,acc[1][1]); \
  acc[1][2]=fmaf(qv.y,pv.z,acc[1][2]); acc[1][3]=fmaf(qv.y,pv.w,acc[1][3]); \
  acc[2][0]=fmaf(qv.z,pv.x,acc[2][0]); acc[2][1]=fmaf(qv.z,pv.y,acc[2][1]); \
  acc[2][2]=fmaf(qv.z,pv.z,acc[2][2]); acc[2][3]=fmaf(qv.z,pv.w,acc[2][3]); \
  acc[3][0]=fmaf(qv.w,pv.x,acc[3][0]); acc[3][1]=fmaf(qv.w,pv.y,acc[3][1]); \
  acc[3][2]=fmaf(qv.w,pv.z,acc[3][2]); acc[3][3]=fmaf(qv.w,pv.w,acc[3][3]);

// ---------------- hidden0 = x @ W_in + b_in ; sq[i] = sum(x_i^2) ----------------
__global__ __launch_bounds__(256) void k_input(const float* __restrict__ x,
    const float* __restrict__ W, const float* __restrict__ b,
    float* __restrict__ hid, float* __restrict__ sq) {
  const int t = threadIdx.x;
  const int i = (blockIdx.x << 1) + (t >> 7);
  const int h = t & 127;
  const float* xr = x + (size_t)i * Fd;
  float acc = 0.f, s = 0.f;
#pragma unroll 8
  for (int f = 0; f < Fd; ++f) {
    float xv = xr[f];
    acc = fmaf(xv, W[f * Hd + h], acc);
    s = fmaf(xv, xv, s);
  }
  hid[(size_t)i * Hd + h] = acc + b[h];
  if (h == 0) sq[i] = s;
}

// ---------------- KNN: per query top-32 nearest + softmax weights ----------------
#define QB 32
#define PB 128
#define DS 129

__global__ __launch_bounds__(256) void k_knn(const float* __restrict__ x,
    const float* __restrict__ sq, int* __restrict__ nidx, float* __restrict__ nw) {
  __shared__ float xqT[Fd][QB];          // queries, transposed  (8 KB)
  __shared__ float xpT[Fd][PB];          // point tile, transposed (32 KB)
  __shared__ float Dt[QB][DS];           // d^2 tile (16.1 KB)
  __shared__ float topd[QB][Kk];         // top-K d^2
  __shared__ unsigned short topi[QB][Kk];// top-K index
  __shared__ float sqq[QB], sqp[PB], taus[QB], maxv[QB];
  __shared__ int maxp[QB], cnt[QB];

  const int t = threadIdx.x;
  const int q0g = blockIdx.x * QB;

  { // stage queries transposed: t -> q=t/8, 8 dims each
    const int q = t >> 3, fb = (t & 7) << 3;
    const float* src = x + (size_t)(q0g + q) * Fd + fb;
    float4 v0 = *(const float4*)(src);
    float4 v1 = *(const float4*)(src + 4);
    xqT[fb + 0][q] = v0.x; xqT[fb + 1][q] = v0.y;
    xqT[fb + 2][q] = v0.z; xqT[fb + 3][q] = v0.w;
    xqT[fb + 4][q] = v1.x; xqT[fb + 5][q] = v1.y;
    xqT[fb + 6][q] = v1.z; xqT[fb + 7][q] = v1.w;
  }
  if (t < QB) {
    sqq[t] = sq[q0g + t];
    taus[t] = INFINITY;
    maxv[t] = -1.0f;
    maxp[t] = 0;
    cnt[t] = 0;
  }
  __syncthreads();

  const int qg = t >> 5, pg = t & 31;
  const int q0 = qg << 2, p0 = pg << 2;
  const int qs = t >> 3, sl = t & 7;     // phase-2 mapping: 8 scan lanes / query

  for (int tile = 0; tile < Nn / PB; ++tile) {
    const int p0g = tile * PB;
    { // stage point tile transposed: t -> p=t/2, 32 dims each
      const int p = t >> 1, fb = (t & 1) << 5;
      const float* src = x + (size_t)(p0g + p) * Fd + fb;
#pragma unroll
      for (int u = 0; u < 8; ++u) {
        float4 v = *(const float4*)(src + (u << 2));
        const int f = fb + (u << 2);
        xpT[f + 0][p] = v.x; xpT[f + 1][p] = v.y;
        xpT[f + 2][p] = v.z; xpT[f + 3][p] = v.w;
      }
      if (t < PB) sqp[t] = sq[p0g + t];
    }
    __syncthreads();
    { // phase 1: 32x128 distance tile, 4x4 micro-tile per thread
      float acc[4][4] = {};
#pragma unroll 4
      for (int f = 0; f < Fd; ++f) {
        float4 qv = *(const float4*)&xqT[f][q0];
        float4 pv = *(const float4*)&xpT[f][p0];
        FMA16(acc, qv, pv)
      }
#pragma unroll
      for (int a = 0; a < 4; ++a) {
        const float sa = sqq[q0 + a];
#pragma unroll
        for (int b = 0; b < 4; ++b) {
          float d2 = fmaf(-2.0f, acc[a][b], sa + sqp[p0 + b]);
          d2 = fmaxf(d2, 0.0f);
          if (q0g + q0 + a == p0g + p0 + b) d2 = INFINITY;  // exclude self
          Dt[q0 + a][p0 + b] = d2;
        }
      }
    }
    __syncthreads();
    { // phase 2: filter + rare serialized insert (8 lanes per query)
      const float tau = taus[qs];
      const int jb = sl << 4;
      unsigned mask = 0u;
#pragma unroll
      for (int jj = 0; jj < 16; ++jj) {
        if (Dt[qs][jb + jj] < tau) mask |= (1u << jj);
      }
      for (int r = 0; r < 8; ++r) {
        if (sl == r && mask) {
          for (int jj = 0; jj < 16; ++jj) {
            if (!(mask & (1u << jj))) continue;
            const float d2 = Dt[qs][jb + jj];
            const int c = cnt[qs];
            if (c < Kk) {
              topd[qs][c] = d2;
              topi[qs][c] = (unsigned short)(p0g + jb + jj);
              if (d2 > maxv[qs]) { maxv[qs] = d2; maxp[qs] = c; }
              cnt[qs] = c + 1;
              if (c + 1 == Kk) taus[qs] = maxv[qs];
            } else if (d2 < taus[qs]) {
              const int mp = maxp[qs];
              topd[qs][mp] = d2;
              topi[qs][mp] = (unsigned short)(p0g + jb + jj);
              float mv = -1.0f; int mpos = 0;
              for (int k2 = 0; k2 < Kk; ++k2) {
                float vv = topd[qs][k2];
                if (vv > mv) { mv = vv; mpos = k2; }
              }
              maxv[qs] = mv; maxp[qs] = mpos; taus[qs] = mv;
            }
          }
        }
      }
    }
    __syncthreads();
  }

  { // finalize: d=sqrt(d2); softmax(-d/TEMP) over the 32 (order-invariant downstream)
    float d[4]; int id[4];
    float mn = INFINITY;
#pragma unroll
    for (int u = 0; u < 4; ++u) {
      const int k2 = (sl << 2) + u;
      d[u] = sqrtf(topd[qs][k2]);
      id[u] = (int)topi[qs][k2];
      mn = fminf(mn, d[u]);
    }
#pragma unroll
    for (int m = 1; m < 8; m <<= 1) mn = fminf(mn, __shfl_xor(mn, m));
    float e[4], s2 = 0.f;
#pragma unroll
    for (int u = 0; u < 4; ++u) { e[u] = __expf((mn - d[u]) * 2.0f); s2 += e[u]; }
#pragma unroll
    for (int m = 1; m < 8; m <<= 1) s2 += __shfl_xor(s2, m);
    const float inv = 1.0f / s2;
#pragma unroll
    for (int u = 0; u < 4; ++u) {
      const int o = (q0g + qs) * Kk + (sl << 2) + u;
      nw[o] = e[u] * inv;
      nidx[o] = id[u];
    }
  }
}

// ---------------- one message-pass step, fused: gather+MLP+LN ----------------
#define RB 32
#define US 36

__global__ __launch_bounds__(256) void k_step(const float* __restrict__ x,
    const float* __restrict__ hin, const int* __restrict__ nidx,
    const float* __restrict__ nw, const float* __restrict__ Wm1,
    const float* __restrict__ bm1, const float* __restrict__ Wm2,
    const float* __restrict__ bm2, const float* __restrict__ g,
    const float* __restrict__ be, float* __restrict__ hout) {
  __shared__ float updT[2 * Hd + Fd][US];  // upd_in transposed: 320 x 36 (46 KB)
  __shared__ float t1T[Hd][US];            // silu(GEMM1) transposed (18 KB)
  const int t = threadIdx.x;
  const int r0 = blockIdx.x * RB;

  { // stage: hidden | agg (gather) | x, all transposed
    const int r = t >> 3, s = t & 7;
    const int i = r0 + r;
    const float* hr = hin + (size_t)i * Hd + (s << 4);
#pragma unroll
    for (int u = 0; u < 4; ++u) {
      float4 v = *(const float4*)(hr + (u << 2));
      const int c = (s << 4) + (u << 2);
      updT[c + 0][r] = v.x; updT[c + 1][r] = v.y;
      updT[c + 2][r] = v.z; updT[c + 3][r] = v.w;
    }
    float a[16];
#pragma unroll
    for (int u = 0; u < 16; ++u) a[u] = 0.f;
    const int* ir = nidx + i * Kk;
    const float* wr = nw + i * Kk;
    for (int k = 0; k < Kk; ++k) {
      const float wk = wr[k];
      const float* hv = hin + (size_t)ir[k] * Hd + (s << 4);
#pragma unroll
      for (int u = 0; u < 4; ++u) {
        float4 v = *(const float4*)(hv + (u << 2));
        a[(u << 2) + 0] = fmaf(wk, v.x, a[(u << 2) + 0]);
        a[(u << 2) + 1] = fmaf(wk, v.y, a[(u << 2) + 1]);
        a[(u << 2) + 2] = fmaf(wk, v.z, a[(u << 2) + 2]);
        a[(u << 2) + 3] = fmaf(wk, v.w, a[(u << 2) + 3]);
      }
    }
#pragma unroll
    for (int u = 0; u < 16; ++u) updT[Hd + (s << 4) + u][r] = a[u];
    const float* xr = x + (size_t)i * Fd + (s << 3);
    float4 x0 = *(const float4*)(xr);
    float4 x1 = *(const float4*)(xr + 4);
    const int c = 2 * Hd + (s << 3);
    updT[c + 0][r] = x0.x; updT[c + 1][r] = x0.y;
    updT[c + 2][r] = x0.z; updT[c + 3][r] = x0.w;
    updT[c + 4][r] = x1.x; updT[c + 5][r] = x1.y;
    updT[c + 6][r] = x1.z; updT[c + 7][r] = x1.w;
  }
  __syncthreads();

  const int rg = t >> 5, cg = t & 31;
  const int rr = rg << 2, cc = cg << 2;
  { // GEMM1 [32x320]x[320x128] + silu -> t1T
    float acc[4][4] = {};
#pragma unroll 4
    for (int k = 0; k < 2 * Hd + Fd; ++k) {
      float4 uv = *(const float4*)&updT[k][rr];
      float4 wv = *(const float4*)&Wm1[k * Hd + cc];
      FMA16(acc, uv, wv)
    }
    float4 b1 = *(const float4*)&bm1[cc];
    float bb1[4] = {b1.x, b1.y, b1.z, b1.w};
#pragma unroll
    for (int a = 0; a < 4; ++a)
#pragma unroll
      for (int b = 0; b < 4; ++b) {
        const float z = acc[a][b] + bb1[b];
        t1T[cc + b][rr + a] = z / (1.0f + __expf(-z));
      }
  }
  __syncthreads();
  { // GEMM2 [32x128]x[128x128] + residual + LayerNorm
    float acc[4][4] = {};
#pragma unroll 4
    for (int k = 0; k < Hd; ++k) {
      float4 uv = *(const float4*)&t1T[k][rr];
      float4 wv = *(const float4*)&Wm2[k * Hd + cc];
      FMA16(acc, uv, wv)
    }
    float4 b2 = *(const float4*)&bm2[cc];
    float bb2[4] = {b2.x, b2.y, b2.z, b2.w};
    float v[4][4];
#pragma unroll
    for (int b = 0; b < 4; ++b) {
      float4 hres = *(const float4*)&updT[cc + b][rr];  // residual = staged hidden
      v[0][b] = hres.x + acc[0][b] + bb2[b];
      v[1][b] = hres.y + acc[1][b] + bb2[b];
      v[2][b] = hres.z + acc[2][b] + bb2[b];
      v[3][b] = hres.w + acc[3][b] + bb2[b];
    }
    float4 gv = *(const float4*)&g[cc];
    float4 bev = *(const float4*)&be[cc];
    float gg[4] = {gv.x, gv.y, gv.z, gv.w};
    float eb[4] = {bev.x, bev.y, bev.z, bev.w};
#pragma unroll
    for (int a = 0; a < 4; ++a) {
      float sm = v[a][0] + v[a][1] + v[a][2] + v[a][3];
      float s2 = 0.f;
#pragma unroll
      for (int b = 0; b < 4; ++b) s2 = fmaf(v[a][b], v[a][b], s2);
#pragma unroll
      for (int m = 1; m < 32; m <<= 1) {
        sm += __shfl_xor(sm, m);
        s2 += __shfl_xor(s2, m);
      }
      const float mean = sm * (1.0f / 128.0f);
      const float var = fmaxf(s2 * (1.0f / 128.0f) - mean * mean, 0.0f);
      const float rstd = rsqrtf(var + 1e-5f);
      float4 o;
      o.x = (v[a][0] - mean) * rstd * gg[0] + eb[0];
      o.y = (v[a][1] - mean) * rstd * gg[1] + eb[1];
      o.z = (v[a][2] - mean) * rstd * gg[2] + eb[2];
      o.w = (v[a][3] - mean) * rstd * gg[3] + eb[3];
      *(float4*)&hout[(size_t)(r0 + rr + a) * Hd + cc] = o;
    }
  }
}

// ---------------- readout: softplus(silu([h,x]@Wr1+b)@Wr2+b) ----------------
__global__ __launch_bounds__(256) void k_out(const float* __restrict__ x,
    const float* __restrict__ hin, const float* __restrict__ Wr1,
    const float* __restrict__ br1, const float* __restrict__ Wr2,
    const float* __restrict__ br2, float* __restrict__ out) {
  __shared__ float rT[Hd + Fd][US];  // 192 x 36 (27 KB)
  const int t = threadIdx.x;
  const int r0 = blockIdx.x * RB;
  {
    const int r = t >> 3, s = t & 7;
    const int i = r0 + r;
    const float* hr = hin + (size_t)i * Hd + (s << 4);
#pragma unroll
    for (int u = 0; u < 4; ++u) {
      float4 v = *(const float4*)(hr + (u << 2));
      const int c = (s << 4) + (u << 2);
      rT[c + 0][r] = v.x; rT[c + 1][r] = v.y;
      rT[c + 2][r] = v.z; rT[c + 3][r] = v.w;
    }
    const float* xr = x + (size_t)i * Fd + (s << 3);
    float4 x0 = *(const float4*)(xr);
    float4 x1 = *(const float4*)(xr + 4);
    const int c = Hd + (s << 3);
    rT[c + 0][r] = x0.x; rT[c + 1][r] = x0.y;
    rT[c + 2][r] = x0.z; rT[c + 3][r] = x0.w;
    rT[c + 4][r] = x1.x; rT[c + 5][r] = x1.y;
    rT[c + 6][r] = x1.z; rT[c + 7][r] = x1.w;
  }
  __syncthreads();
  const int rg = t >> 5, cg = t & 31;
  const int rr = rg << 2, cc = cg << 2;
  float acc[4][4] = {};
#pragma unroll 4
  for (int k = 0; k < Hd + Fd; ++k) {
    float4 uv = *(const float4*)&rT[k][rr];
    float4 wv = *(const float4*)&Wr1[k * Hd + cc];
    FMA16(acc, uv, wv)
  }
  float4 b1 = *(const float4*)&br1[cc];
  float bb1[4] = {b1.x, b1.y, b1.z, b1.w};
  float4 w2 = *(const float4*)&Wr2[cc];
  float ww[4] = {w2.x, w2.y, w2.z, w2.w};
  float part[4];
#pragma unroll
  for (int a = 0; a < 4; ++a) {
    part[a] = 0.f;
#pragma unroll
    for (int b = 0; b < 4; ++b) {
      const float z = acc[a][b] + bb1[b];
      const float sil = z / (1.0f + __expf(-z));
      part[a] = fmaf(sil, ww[b], part[a]);
    }
  }
#pragma unroll
  for (int m = 1; m < 32; m <<= 1) {
#pragma unroll
    for (int a = 0; a < 4; ++a) part[a] += __shfl_xor(part[a], m);
  }
  if (cg == 0) {
    const float bias = br2[0];
#pragma unroll
    for (int a = 0; a < 4; ++a) {
      const float rv = part[a] + bias;
      out[r0 + rr + a] = fmaxf(rv, 0.0f) + log1pf(__expf(-fabsf(rv)));
    }
  }
}

extern "C" void kernel_launch(void* const* d_in, const int* in_sizes, int n_in,
                              void* d_out, int out_size, void* d_ws, size_t ws_size,
                              hipStream_t stream) {
  const float* x    = (const float*)d_in[0];
  const float* W_in = (const float*)d_in[1];
  const float* b_in = (const float*)d_in[2];
  const float* W_m1 = (const float*)d_in[3];
  const float* b_m1 = (const float*)d_in[4];
  const float* W_m2 = (const float*)d_in[5];
  const float* b_m2 = (const float*)d_in[6];
  const float* ln_g = (const float*)d_in[7];
  const float* ln_b = (const float*)d_in[8];
  const float* W_r1 = (const float*)d_in[9];
  const float* b_r1 = (const float*)d_in[10];
  const float* W_r2 = (const float*)d_in[11];
  const float* b_r2 = (const float*)d_in[12];
  float* out = (float*)d_out;

  char* ws = (char*)d_ws;
  float* hidA = (float*)(ws);                          // 8 MB
  float* hidB = (float*)(ws + ((size_t)8 << 20));      // 8 MB
  float* sq   = (float*)(ws + ((size_t)16 << 20));     // 64 KB
  int*   nidx = (int*)  (ws + ((size_t)17 << 20));     // 2 MB
  float* nw   = (float*)(ws + ((size_t)19 << 20));     // 2 MB

  k_input<<<dim3(Nn / 2), dim3(256), 0, stream>>>(x, W_in, b_in, hidA, sq);
  k_knn<<<dim3(Nn / QB), dim3(256), 0, stream>>>(x, sq, nidx, nw);
  k_step<<<dim3(Nn / RB), dim3(256), 0, stream>>>(x, hidA, nidx, nw, W_m1, b_m1,
                                                  W_m2, b_m2, ln_g, ln_b, hidB);
  k_step<<<dim3(Nn / RB), dim3(256), 0, stream>>>(x, hidB, nidx, nw, W_m1, b_m1,
                                                  W_m2, b_m2, ln_g, ln_b, hidA);
  k_out<<<dim3(Nn / RB), dim3(256), 0, stream>>>(x, hidA, W_r1, b_r1, W_r2, b_r2, out);
}

// Round 2
// 840.286 us; speedup vs baseline: 2.3691x; 2.3691x over previous
//
#include <hip/hip_runtime.h>
#include <math.h>

#define Nn 16384
#define Fd 64
#define Hd 128
#define Kk 32

typedef short bfrag __attribute__((ext_vector_type(8)));    // 8 bf16 = 4 VGPR
typedef float f32x16 __attribute__((ext_vector_type(16)));  // MFMA 32x32 acc

#define FMA16(acc, qv, pv) \
  acc[0][0]=fmaf(qv.x,pv.x,acc[0][0]); acc[0][1]=fmaf(qv.x,pv.y,acc[0][1]); \
  acc[0][2]=fmaf(qv.x,pv.z,acc[0][2]); acc[0][3]=fmaf(qv.x,pv.w,acc[0][3]); \
  acc[1][0]=fmaf(qv.y,pv.x,acc[1][0]); acc[1][1]=fmaf(qv.y,pv.y,acc[1][1]); \
  acc[1][2]=fmaf(qv.y,pv.z,acc[1][2]); acc[1][3]=fmaf(qv.y,pv.w,acc[1][3]); \
  acc[2][0]=fmaf(qv.z,pv.x,acc[2][0]); acc[2][1]=fmaf(qv.z,pv.y,acc[2][1]); \
  acc[2][2]=fmaf(qv.z,pv.z,acc[2][2]); acc[2][3]=fmaf(qv.z,pv.w,acc[2][3]); \
  acc[3][0]=fmaf(qv.w,pv.x,acc[3][0]); acc[3][1]=fmaf(qv.w,pv.y,acc[3][1]); \
  acc[3][2]=fmaf(qv.w,pv.z,acc[3][2]); acc[3][3]=fmaf(qv.w,pv.w,acc[3][3]);

// ---------------- hidden0 = x @ W_in + b_in ; sq[i] = sum(x_i^2) ----------------
__global__ __launch_bounds__(256) void k_input(const float* __restrict__ x,
    const float* __restrict__ W, const float* __restrict__ b,
    float* __restrict__ hid, float* __restrict__ sq) {
  const int t = threadIdx.x;
  const int i = (blockIdx.x << 1) + (t >> 7);
  const int h = t & 127;
  const float* xr = x + (size_t)i * Fd;
  float acc = 0.f, s = 0.f;
#pragma unroll 8
  for (int f = 0; f < Fd; ++f) {
    float xv = xr[f];
    acc = fmaf(xv, W[f * Hd + h], acc);
    s = fmaf(xv, xv, s);
  }
  hid[(size_t)i * Hd + h] = acc + b[h];
  if (h == 0) sq[i] = s;
}

// ------------- precompute x as bf16 hi/lo in MFMA-fragment order -------------
// Layout: per 32-point group g (4KB region): elem idx = sub*256 + (p&31)*8 + j
// where sub = (k>>3)  (k = 16*s + 8*h + j).  Wave reads 16B at lane*16.
__global__ __launch_bounds__(256) void k_prep(const float* __restrict__ x,
    short* __restrict__ xh, short* __restrict__ xl) {
  const int gid = blockIdx.x * 256 + threadIdx.x;
  const int p = gid >> 3, sub = gid & 7;
  const float* src = x + (size_t)p * Fd + sub * 8;
  float4 v0 = *(const float4*)src;
  float4 v1 = *(const float4*)(src + 4);
  float vv[8] = {v0.x, v0.y, v0.z, v0.w, v1.x, v1.y, v1.z, v1.w};
  bfrag hi, lo;
#pragma unroll
  for (int j = 0; j < 8; ++j) {
    unsigned u = __float_as_uint(vv[j]);
    unsigned r = u + 0x7fffu + ((u >> 16) & 1u);
    unsigned short hb = (unsigned short)(r >> 16);
    float hf = __uint_as_float((unsigned)hb << 16);
    float lof = vv[j] - hf;
    unsigned ul = __float_as_uint(lof);
    unsigned rl = ul + 0x7fffu + ((ul >> 16) & 1u);
    hi[j] = (short)hb;
    lo[j] = (short)(rl >> 16);
  }
  const size_t o = (size_t)(p >> 5) * 2048 + (size_t)sub * 256 + (size_t)(p & 31) * 8;
  *(bfrag*)(xh + o) = hi;
  *(bfrag*)(xl + o) = lo;
}

// ---------------- KNN: MFMA distance GEMM + streaming exact top-32 ----------------
// Block: 512 thr (8 waves), 64 queries, 256-point tiles, 64 tiles.
// Wave w: point sub-group w (32 pts) x both query groups via mfma_32x32x16_bf16.
// d2 stays in acc regs; cand iff acc > thrRow + 0.5*sq_p; rare pushes into
// per-query LDS queues (cap 96), drained by 64 owner threads (waves 0 & 4).
#define QCAP 96
#define QSTR 97

__global__ __launch_bounds__(512, 2) void k_knn(const short* __restrict__ xbhi,
    const short* __restrict__ xblo, const float* __restrict__ sq,
    unsigned short* __restrict__ nidx, float* __restrict__ nw) {
  __shared__ __align__(16) float qds[64 * QSTR];
  __shared__ unsigned short qis[64 * QSTR];
  __shared__ __align__(16) float topd[64 * 33];
  __shared__ unsigned short topi[64 * 33];
  __shared__ __align__(16) float sqq_s[64];
  __shared__ __align__(16) float thrRow[64];
  __shared__ unsigned qcnt[64];

  const int t = threadIdx.x;
  const int w = t >> 6;
  const int lane = t & 63;
  const int h = lane >> 5;
  const int col = lane & 31;
  const int qg0 = blockIdx.x * 64;
  const int selfTileIdx = (int)(blockIdx.x >> 2);

  for (int i = t; i < 64 * 33; i += 512) { topd[i] = 1e30f; topi[i] = 0; }
  if (t < 64) { sqq_s[t] = sq[qg0 + t]; thrRow[t] = -5e29f; qcnt[t] = 0; }

  // owner bookkeeping (waves 0 and 4 -> 2 SIMDs share the serial insert work)
  const int ownq = (t < 32) ? t : ((t >= 256 && t < 288) ? (t - 256 + 32) : -1);
  float mv = 1e30f; int mp = 0; int ocnt = 0;
  const float sqqR = (ownq >= 0) ? sq[qg0 + ownq] : 0.f;

  const char* xh = (const char*)xbhi;
  const char* xl = (const char*)xblo;

  // A fragments (both query groups, hi+lo), resident in regs
  bfrag ahi0[4], alo0[4], ahi1[4], alo1[4];
  {
    const size_t a0 = (size_t)(blockIdx.x * 2 + 0) * 4096 + (size_t)lane * 16;
    const size_t a1 = (size_t)(blockIdx.x * 2 + 1) * 4096 + (size_t)lane * 16;
#pragma unroll
    for (int s = 0; s < 4; ++s) {
      ahi0[s] = *(const bfrag*)(xh + a0 + s * 1024);
      alo0[s] = *(const bfrag*)(xl + a0 + s * 1024);
      ahi1[s] = *(const bfrag*)(xh + a1 + s * 1024);
      alo1[s] = *(const bfrag*)(xl + a1 + s * 1024);
    }
  }
  __syncthreads();

#define LOADB(TL, BH, BL, SPD) { \
  const size_t bb_ = (size_t)((TL) * 8 + w) * 4096 + (size_t)lane * 16; \
  _Pragma("unroll") for (int s_ = 0; s_ < 4; ++s_) { \
    BH[s_] = *(const bfrag*)(xh + bb_ + s_ * 1024); \
    BL[s_] = *(const bfrag*)(xl + bb_ + s_ * 1024); } \
  SPD = sq[(TL) * 256 + w * 32 + col]; }

#define RESCAN { mv = -1.0f; mp = 0; \
  for (int k_ = 0; k_ < 32; ++k_) { float v_ = topd[ownq * 33 + k_]; \
    if (v_ > mv) { mv = v_; mp = k_; } } }

#define INSERT(FIXEDN) { \
  if (ownq >= 0) { \
    int n_ = ((FIXEDN) >= 0) ? (FIXEDN) : (int)qcnt[ownq]; \
    if (n_ > QCAP) n_ = QCAP; \
    for (int e_ = 0; e_ < n_; ++e_) { \
      float d_ = qds[ownq * QSTR + e_]; \
      if (ocnt < 32) { \
        topd[ownq * 33 + ocnt] = d_; topi[ownq * 33 + ocnt] = qis[ownq * QSTR + e_]; \
        ocnt++; \
        if (ocnt == 32) { RESCAN } \
      } else if (d_ < mv) { \
        topd[ownq * 33 + mp] = d_; topi[ownq * 33 + mp] = qis[ownq * QSTR + e_]; \
        RESCAN \
      } } \
    if ((FIXEDN) < 0 && n_ > 0) qcnt[ownq] = 0; \
    if (ocnt == 32) thrRow[ownq] = 0.5f * (sqqR - mv); \
  } }

  // candidate iff d2 < tau  <=>  acc > 0.5*(sqq - tau) + 0.5*sqp
#define PUSHQ(ACC, QG, TL, SPv) { \
  const float sph_ = 0.5f * (SPv); \
  _Pragma("unroll") for (int m_ = 0; m_ < 4; ++m_) { \
    const float4 th_ = *(const float4*)&thrRow[(QG) * 32 + m_ * 8 + h * 4]; \
    _Pragma("unroll") for (int b_ = 0; b_ < 4; ++b_) { \
      const float av_ = ACC[m_ * 4 + b_]; \
      const float tb_ = (b_ == 0) ? th_.x : (b_ == 1) ? th_.y : (b_ == 2) ? th_.z : th_.w; \
      if (av_ > tb_ + sph_) { \
        const int qq_ = (QG) * 32 + b_ + 8 * m_ + 4 * h; \
        const int p_ = (TL) * 256 + w * 32 + col; \
        if (!(selfT_ && p_ == qg0 + qq_)) { \
          const float d2_ = fmaxf(sqq_s[qq_] + (SPv)-2.0f * av_, 0.0f); \
          const unsigned sl_ = atomicAdd(&qcnt[qq_], 1u); \
          if (sl_ < (unsigned)QCAP) { \
            qds[qq_ * QSTR + sl_] = d2_; qis[qq_ * QSTR + sl_] = (unsigned short)p_; } \
        } } } } }

  // tile 0, waves 0-2: every (q,p) slot is unique (p in [0,96)) -> no atomics
#define PUSH0(ACC, QG, SPv) { \
  _Pragma("unroll") for (int m_ = 0; m_ < 4; ++m_) { \
    _Pragma("unroll") for (int b_ = 0; b_ < 4; ++b_) { \
      const float av_ = ACC[m_ * 4 + b_]; \
      const int qq_ = (QG) * 32 + b_ + 8 * m_ + 4 * h; \
      const int p_ = w * 32 + col; \
      float d2_ = fmaxf(sqq_s[qq_] + (SPv)-2.0f * av_, 0.0f); \
      if (selfT_ && p_ == qg0 + qq_) d2_ = 1e30f; \
      qds[qq_ * QSTR + p_] = d2_; qis[qq_ * QSTR + p_] = (unsigned short)p_; } } }

#define BODY(TL, BH, BL, SPC, NBH, NBL, NSPC) { \
  const int tl_ = (TL); \
  if (tl_ + 1 < 64) LOADB(tl_ + 1, NBH, NBL, NSPC); \
  f32x16 a0, a1; \
  _Pragma("unroll") for (int i_ = 0; i_ < 16; ++i_) { a0[i_] = 0.f; a1[i_] = 0.f; } \
  _Pragma("unroll") for (int s_ = 0; s_ < 4; ++s_) { \
    a0 = __builtin_amdgcn_mfma_f32_32x32x16_bf16(ahi0[s_], BH[s_], a0, 0, 0, 0); \
    a1 = __builtin_amdgcn_mfma_f32_32x32x16_bf16(ahi1[s_], BH[s_], a1, 0, 0, 0); } \
  _Pragma("unroll") for (int s_ = 0; s_ < 4; ++s_) { \
    a0 = __builtin_amdgcn_mfma_f32_32x32x16_bf16(ahi0[s_], BL[s_], a0, 0, 0, 0); \
    a1 = __builtin_amdgcn_mfma_f32_32x32x16_bf16(ahi1[s_], BL[s_], a1, 0, 0, 0); } \
  _Pragma("unroll") for (int s_ = 0; s_ < 4; ++s_) { \
    a0 = __builtin_amdgcn_mfma_f32_32x32x16_bf16(alo0[s_], BH[s_], a0, 0, 0, 0); \
    a1 = __builtin_amdgcn_mfma_f32_32x32x16_bf16(alo1[s_], BH[s_], a1, 0, 0, 0); } \
  const bool selfT_ = (tl_ == selfTileIdx); \
  if (tl_ == 0) { \
    if (w < 3) { PUSH0(a0, 0, SPC) PUSH0(a1, 1, SPC) } \
    __syncthreads(); INSERT(96) __syncthreads(); \
    if (w >= 3 && w < 6) { PUSHQ(a0, 0, tl_, SPC) PUSHQ(a1, 1, tl_, SPC) } \
    __syncthreads(); INSERT(-1) __syncthreads(); \
    if (w >= 6) { PUSHQ(a0, 0, tl_, SPC) PUSHQ(a1, 1, tl_, SPC) } \
    __syncthreads(); INSERT(-1) __syncthreads(); \
  } else { \
    PUSHQ(a0, 0, tl_, SPC) PUSHQ(a1, 1, tl_, SPC) \
    __syncthreads(); INSERT(-1) __syncthreads(); \
  } }

  bfrag bh0[4], bl0[4], bh1[4], bl1[4];
  float sp0v = 0.f, sp1v = 0.f;
  LOADB(0, bh0, bl0, sp0v);
  for (int tp = 0; tp < 64; tp += 2) {
    BODY(tp, bh0, bl0, sp0v, bh1, bl1, sp1v);
    BODY(tp + 1, bh1, bl1, sp1v, bh0, bl0, sp0v);
  }

  // finalize: d=sqrt(d2), softmax(-2d) over the 32 slots (order-invariant)
  {
    const int qq = t >> 3, sl = t & 7;
    float d[4]; int id[4];
    float mn = 1e30f;
#pragma unroll
    for (int u = 0; u < 4; ++u) {
      const int k2 = sl * 4 + u;
      d[u] = sqrtf(topd[qq * 33 + k2]);
      id[u] = (int)topi[qq * 33 + k2];
      mn = fminf(mn, d[u]);
    }
#pragma unroll
    for (int m = 1; m < 8; m <<= 1) mn = fminf(mn, __shfl_xor(mn, m));
    float e[4], s2 = 0.f;
#pragma unroll
    for (int u = 0; u < 4; ++u) { e[u] = __expf((mn - d[u]) * 2.0f); s2 += e[u]; }
#pragma unroll
    for (int m = 1; m < 8; m <<= 1) s2 += __shfl_xor(s2, m);
    const float inv = 1.0f / s2;
#pragma unroll
    for (int u = 0; u < 4; ++u) {
      const int o = (qg0 + qq) * Kk + sl * 4 + u;
      nw[o] = e[u] * inv;
      nidx[o] = (unsigned short)id[u];
    }
  }
#undef LOADB
#undef RESCAN
#undef INSERT
#undef PUSHQ
#undef PUSH0
#undef BODY
}

// ---------------- one message-pass step, fused: gather+MLP+LN ----------------
#define RB 32
#define US 36

__global__ __launch_bounds__(256) void k_step(const float* __restrict__ x,
    const float* __restrict__ hin, const unsigned short* __restrict__ nidx,
    const float* __restrict__ nw, const float* __restrict__ Wm1,
    const float* __restrict__ bm1, const float* __restrict__ Wm2,
    const float* __restrict__ bm2, const float* __restrict__ g,
    const float* __restrict__ be, float* __restrict__ hout) {
  __shared__ float updT[2 * Hd + Fd][US];  // upd_in transposed: 320 x 36 (46 KB)
  __shared__ float t1T[Hd][US];            // silu(GEMM1) transposed (18 KB)
  const int t = threadIdx.x;
  const int r0 = blockIdx.x * RB;

  { // stage: hidden | agg (gather) | x, all transposed
    const int r = t >> 3, s = t & 7;
    const int i = r0 + r;
    const float* hr = hin + (size_t)i * Hd + (s << 4);
#pragma unroll
    for (int u = 0; u < 4; ++u) {
      float4 v = *(const float4*)(hr + (u << 2));
      const int c = (s << 4) + (u << 2);
      updT[c + 0][r] = v.x; updT[c + 1][r] = v.y;
      updT[c + 2][r] = v.z; updT[c + 3][r] = v.w;
    }
    float a[16];
#pragma unroll
    for (int u = 0; u < 16; ++u) a[u] = 0.f;
    const unsigned short* ir = nidx + i * Kk;
    const float* wr = nw + i * Kk;
    for (int k = 0; k < Kk; ++k) {
      const float wk = wr[k];
      const float* hv = hin + (size_t)ir[k] * Hd + (s << 4);
#pragma unroll
      for (int u = 0; u < 4; ++u) {
        float4 v = *(const float4*)(hv + (u << 2));
        a[(u << 2) + 0] = fmaf(wk, v.x, a[(u << 2) + 0]);
        a[(u << 2) + 1] = fmaf(wk, v.y, a[(u << 2) + 1]);
        a[(u << 2) + 2] = fmaf(wk, v.z, a[(u << 2) + 2]);
        a[(u << 2) + 3] = fmaf(wk, v.w, a[(u << 2) + 3]);
      }
    }
#pragma unroll
    for (int u = 0; u < 16; ++u) updT[Hd + (s << 4) + u][r] = a[u];
    const float* xr = x + (size_t)i * Fd + (s << 3);
    float4 x0 = *(const float4*)(xr);
    float4 x1 = *(const float4*)(xr + 4);
    const int c = 2 * Hd + (s << 3);
    updT[c + 0][r] = x0.x; updT[c + 1][r] = x0.y;
    updT[c + 2][r] = x0.z; updT[c + 3][r] = x0.w;
    updT[c + 4][r] = x1.x; updT[c + 5][r] = x1.y;
    updT[c + 6][r] = x1.z; updT[c + 7][r] = x1.w;
  }
  __syncthreads();

  const int rg = t >> 5, cg = t & 31;
  const int rr = rg << 2, cc = cg << 2;
  { // GEMM1 [32x320]x[320x128] + silu -> t1T
    float acc[4][4] = {};
#pragma unroll 4
    for (int k = 0; k < 2 * Hd + Fd; ++k) {
      float4 uv = *(const float4*)&updT[k][rr];
      float4 wv = *(const float4*)&Wm1[k * Hd + cc];
      FMA16(acc, uv, wv)
    }
    float4 b1 = *(const float4*)&bm1[cc];
    float bb1[4] = {b1.x, b1.y, b1.z, b1.w};
#pragma unroll
    for (int a = 0; a < 4; ++a)
#pragma unroll
      for (int b = 0; b < 4; ++b) {
        const float z = acc[a][b] + bb1[b];
        t1T[cc + b][rr + a] = z / (1.0f + __expf(-z));
      }
  }
  __syncthreads();
  { // GEMM2 [32x128]x[128x128] + residual + LayerNorm
    float acc[4][4] = {};
#pragma unroll 4
    for (int k = 0; k < Hd; ++k) {
      float4 uv = *(const float4*)&t1T[k][rr];
      float4 wv = *(const float4*)&Wm2[k * Hd + cc];
      FMA16(acc, uv, wv)
    }
    float4 b2 = *(const float4*)&bm2[cc];
    float bb2[4] = {b2.x, b2.y, b2.z, b2.w};
    float v[4][4];
#pragma unroll
    for (int b = 0; b < 4; ++b) {
      float4 hres = *(const float4*)&updT[cc + b][rr];  // residual = staged hidden
      v[0][b] = hres.x + acc[0][b] + bb2[b];
      v[1][b] = hres.y + acc[1][b] + bb2[b];
      v[2][b] = hres.z + acc[2][b] + bb2[b];
      v[3][b] = hres.w + acc[3][b] + bb2[b];
    }
    float4 gv = *(const float4*)&g[cc];
    float4 bev = *(const float4*)&be[cc];
    float gg[4] = {gv.x, gv.y, gv.z, gv.w};
    float eb[4] = {bev.x, bev.y, bev.z, bev.w};
#pragma unroll
    for (int a = 0; a < 4; ++a) {
      float sm = v[a][0] + v[a][1] + v[a][2] + v[a][3];
      float s2 = 0.f;
#pragma unroll
      for (int b = 0; b < 4; ++b) s2 = fmaf(v[a][b], v[a][b], s2);
#pragma unroll
      for (int m = 1; m < 32; m <<= 1) {
        sm += __shfl_xor(sm, m);
        s2 += __shfl_xor(s2, m);
      }
      const float mean = sm * (1.0f / 128.0f);
      const float var = fmaxf(s2 * (1.0f / 128.0f) - mean * mean, 0.0f);
      const float rstd = rsqrtf(var + 1e-5f);
      float4 o;
      o.x = (v[a][0] - mean) * rstd * gg[0] + eb[0];
      o.y = (v[a][1] - mean) * rstd * gg[1] + eb[1];
      o.z = (v[a][2] - mean) * rstd * gg[2] + eb[2];
      o.w = (v[a][3] - mean) * rstd * gg[3] + eb[3];
      *(float4*)&hout[(size_t)(r0 + rr + a) * Hd + cc] = o;
    }
  }
}

// ---------------- readout: softplus(silu([h,x]@Wr1+b)@Wr2+b) ----------------
__global__ __launch_bounds__(256) void k_out(const float* __restrict__ x,
    const float* __restrict__ hin, const float* __restrict__ Wr1,
    const float* __restrict__ br1, const float* __restrict__ Wr2,
    const float* __restrict__ br2, float* __restrict__ out) {
  __shared__ float rT[Hd + Fd][US];  // 192 x 36 (27 KB)
  const int t = threadIdx.x;
  const int r0 = blockIdx.x * RB;
  {
    const int r = t >> 3, s = t & 7;
    const int i = r0 + r;
    const float* hr = hin + (size_t)i * Hd + (s << 4);
#pragma unroll
    for (int u = 0; u < 4; ++u) {
      float4 v = *(const float4*)(hr + (u << 2));
      const int c = (s << 4) + (u << 2);
      rT[c + 0][r] = v.x; rT[c + 1][r] = v.y;
      rT[c + 2][r] = v.z; rT[c + 3][r] = v.w;
    }
    const float* xr = x + (size_t)i * Fd + (s << 3);
    float4 x0 = *(const float4*)(xr);
    float4 x1 = *(const float4*)(xr + 4);
    const int c = Hd + (s << 3);
    rT[c + 0][r] = x0.x; rT[c + 1][r] = x0.y;
    rT[c + 2][r] = x0.z; rT[c + 3][r] = x0.w;
    rT[c + 4][r] = x1.x; rT[c + 5][r] = x1.y;
    rT[c + 6][r] = x1.z; rT[c + 7][r] = x1.w;
  }
  __syncthreads();
  const int rg = t >> 5, cg = t & 31;
  const int rr = rg << 2, cc = cg << 2;
  float acc[4][4] = {};
#pragma unroll 4
  for (int k = 0; k < Hd + Fd; ++k) {
    float4 uv = *(const float4*)&rT[k][rr];
    float4 wv = *(const float4*)&Wr1[k * Hd + cc];
    FMA16(acc, uv, wv)
  }
  float4 b1 = *(const float4*)&br1[cc];
  float bb1[4] = {b1.x, b1.y, b1.z, b1.w};
  float4 w2 = *(const float4*)&Wr2[cc];
  float ww[4] = {w2.x, w2.y, w2.z, w2.w};
  float part[4];
#pragma unroll
  for (int a = 0; a < 4; ++a) {
    part[a] = 0.f;
#pragma unroll
    for (int b = 0; b < 4; ++b) {
      const float z = acc[a][b] + bb1[b];
      const float sil = z / (1.0f + __expf(-z));
      part[a] = fmaf(sil, ww[b], part[a]);
    }
  }
#pragma unroll
  for (int m = 1; m < 32; m <<= 1) {
#pragma unroll
    for (int a = 0; a < 4; ++a) part[a] += __shfl_xor(part[a], m);
  }
  if (cg == 0) {
    const float bias = br2[0];
#pragma unroll
    for (int a = 0; a < 4; ++a) {
      const float rv = part[a] + bias;
      out[r0 + rr + a] = fmaxf(rv, 0.0f) + log1pf(__expf(-fabsf(rv)));
    }
  }
}

extern "C" void kernel_launch(void* const* d_in, const int* in_sizes, int n_in,
                              void* d_out, int out_size, void* d_ws, size_t ws_size,
                              hipStream_t stream) {
  const float* x    = (const float*)d_in[0];
  const float* W_in = (const float*)d_in[1];
  const float* b_in = (const float*)d_in[2];
  const float* W_m1 = (const float*)d_in[3];
  const float* b_m1 = (const float*)d_in[4];
  const float* W_m2 = (const float*)d_in[5];
  const float* b_m2 = (const float*)d_in[6];
  const float* ln_g = (const float*)d_in[7];
  const float* ln_b = (const float*)d_in[8];
  const float* W_r1 = (const float*)d_in[9];
  const float* b_r1 = (const float*)d_in[10];
  const float* W_r2 = (const float*)d_in[11];
  const float* b_r2 = (const float*)d_in[12];
  float* out = (float*)d_out;

  char* ws = (char*)d_ws;
  const size_t MB = (size_t)1 << 20;
  float*          hidA = (float*)(ws);                 // 8 MB
  float*          hidB = (float*)(ws + 8 * MB);        // 8 MB
  short*          xbhi = (short*)(ws + 16 * MB);       // 2 MB
  short*          xblo = (short*)(ws + 18 * MB);       // 2 MB
  unsigned short* nidx = (unsigned short*)(ws + 20 * MB);  // 1 MB
  float*          nw   = (float*)(ws + 21 * MB);       // 2 MB
  float*          sq   = (float*)(ws + 23 * MB);       // 64 KB

  k_input<<<dim3(Nn / 2), dim3(256), 0, stream>>>(x, W_in, b_in, hidA, sq);
  k_prep<<<dim3(Nn * 8 / 256), dim3(256), 0, stream>>>(x, xbhi, xblo);
  k_knn<<<dim3(Nn / 64), dim3(512), 0, stream>>>(xbhi, xblo, sq, nidx, nw);
  k_step<<<dim3(Nn / RB), dim3(256), 0, stream>>>(x, hidA, nidx, nw, W_m1, b_m1,
                                                  W_m2, b_m2, ln_g, ln_b, hidB);
  k_step<<<dim3(Nn / RB), dim3(256), 0, stream>>>(x, hidB, nidx, nw, W_m1, b_m1,
                                                  W_m2, b_m2, ln_g, ln_b, hidA);
  k_out<<<dim3(Nn / RB), dim3(256), 0, stream>>>(x, hidA, W_r1, b_r1, W_r2, b_r2, out);
}

// Round 3
// 703.989 us; speedup vs baseline: 2.8278x; 1.1936x over previous
//
#include <hip/hip_runtime.h>
#include <math.h>

#define Nn 16384
#define Fd 64
#define Hd 128
#define Kk 32

typedef short bfrag __attribute__((ext_vector_type(8)));    // 8 bf16 = 4 VGPR
typedef float f32x16 __attribute__((ext_vector_type(16)));  // MFMA 32x32 acc

#define FMA16(acc, qv, pv) \
  acc[0][0]=fmaf(qv.x,pv.x,acc[0][0]); acc[0][1]=fmaf(qv.x,pv.y,acc[0][1]); \
  acc[0][2]=fmaf(qv.x,pv.z,acc[0][2]); acc[0][3]=fmaf(qv.x,pv.w,acc[0][3]); \
  acc[1][0]=fmaf(qv.y,pv.x,acc[1][0]); acc[1][1]=fmaf(qv.y,pv.y,acc[1][1]); \
  acc[1][2]=fmaf(qv.y,pv.z,acc[1][2]); acc[1][3]=fmaf(qv.y,pv.w,acc[1][3]); \
  acc[2][0]=fmaf(qv.z,pv.x,acc[2][0]); acc[2][1]=fmaf(qv.z,pv.y,acc[2][1]); \
  acc[2][2]=fmaf(qv.z,pv.z,acc[2][2]); acc[2][3]=fmaf(qv.z,pv.w,acc[2][3]); \
  acc[3][0]=fmaf(qv.w,pv.x,acc[3][0]); acc[3][1]=fmaf(qv.w,pv.y,acc[3][1]); \
  acc[3][2]=fmaf(qv.w,pv.z,acc[3][2]); acc[3][3]=fmaf(qv.w,pv.w,acc[3][3]);

// ---------------- hidden0 = x @ W_in + b_in ; sq[i] = sum(x_i^2) ----------------
__global__ __launch_bounds__(256) void k_input(const float* __restrict__ x,
    const float* __restrict__ W, const float* __restrict__ b,
    float* __restrict__ hid, float* __restrict__ sq) {
  const int t = threadIdx.x;
  const int i = (blockIdx.x << 1) + (t >> 7);
  const int h = t & 127;
  const float* xr = x + (size_t)i * Fd;
  float acc = 0.f, s = 0.f;
#pragma unroll 8
  for (int f = 0; f < Fd; ++f) {
    float xv = xr[f];
    acc = fmaf(xv, W[f * Hd + h], acc);
    s = fmaf(xv, xv, s);
  }
  hid[(size_t)i * Hd + h] = acc + b[h];
  if (h == 0) sq[i] = s;
}

// ------------- precompute x as bf16 hi/lo in MFMA-fragment order -------------
__global__ __launch_bounds__(256) void k_prep(const float* __restrict__ x,
    short* __restrict__ xh, short* __restrict__ xl) {
  const int gid = blockIdx.x * 256 + threadIdx.x;
  const int p = gid >> 3, sub = gid & 7;
  const float* src = x + (size_t)p * Fd + sub * 8;
  float4 v0 = *(const float4*)src;
  float4 v1 = *(const float4*)(src + 4);
  float vv[8] = {v0.x, v0.y, v0.z, v0.w, v1.x, v1.y, v1.z, v1.w};
  bfrag hi, lo;
#pragma unroll
  for (int j = 0; j < 8; ++j) {
    unsigned u = __float_as_uint(vv[j]);
    unsigned r = u + 0x7fffu + ((u >> 16) & 1u);
    unsigned short hb = (unsigned short)(r >> 16);
    float hf = __uint_as_float((unsigned)hb << 16);
    float lof = vv[j] - hf;
    unsigned ul = __float_as_uint(lof);
    unsigned rl = ul + 0x7fffu + ((ul >> 16) & 1u);
    hi[j] = (short)hb;
    lo[j] = (short)(rl >> 16);
  }
  const size_t o = (size_t)(p >> 5) * 2048 + (size_t)sub * 256 + (size_t)(p & 31) * 8;
  *(bfrag*)(xh + o) = hi;
  *(bfrag*)(xl + o) = lo;
}

// ---------------- KNN: MFMA distance GEMM + streaming exact top-32 ----------------
#define QCAP 96
#define QSTR 97
#define TSTR 36

__global__ __launch_bounds__(512, 1) void k_knn(const short* __restrict__ xbhi,
    const short* __restrict__ xblo, const float* __restrict__ sq,
    unsigned short* __restrict__ nidx, float* __restrict__ nw) {
  __shared__ __align__(16) float qds[64 * QSTR];
  __shared__ unsigned short qis[64 * QSTR];
  __shared__ __align__(16) float topd[64 * TSTR];
  __shared__ __align__(16) unsigned short topi[64 * TSTR];
  __shared__ __align__(16) float sqq_s[64];
  __shared__ __align__(16) float thrRow[64];
  __shared__ unsigned qcnt[64];

  const int t = threadIdx.x;
  const int w = t >> 6;
  const int lane = t & 63;
  const int h = lane >> 5;
  const int col = lane & 31;
  const int qg0 = blockIdx.x * 64;
  const int selfTileIdx = (int)(blockIdx.x >> 2);

  for (int i = t; i < 64 * TSTR; i += 512) { topd[i] = 1e30f; topi[i] = 0; }
  if (t < 64) { sqq_s[t] = sq[qg0 + t]; thrRow[t] = -5e29f; qcnt[t] = 0; }

  // owner bookkeeping (waves 0 and 4 -> 2 SIMDs share the serial insert work)
  const int ownq = (t < 32) ? t : ((t >= 256 && t < 288) ? (t - 256 + 32) : -1);
  float mv = 1e30f; int mp = 0; int ocnt = 0;
  const float sqqR = (ownq >= 0) ? sq[qg0 + ownq] : 0.f;

  const char* xh = (const char*)xbhi;
  const char* xl = (const char*)xblo;

  // A fragments (both query groups, hi+lo), resident in regs
  bfrag ahi0[4], alo0[4], ahi1[4], alo1[4];
  {
    const size_t a0 = (size_t)(blockIdx.x * 2 + 0) * 4096 + (size_t)lane * 16;
    const size_t a1 = (size_t)(blockIdx.x * 2 + 1) * 4096 + (size_t)lane * 16;
#pragma unroll
    for (int s = 0; s < 4; ++s) {
      ahi0[s] = *(const bfrag*)(xh + a0 + s * 1024);
      alo0[s] = *(const bfrag*)(xl + a0 + s * 1024);
      ahi1[s] = *(const bfrag*)(xh + a1 + s * 1024);
      alo1[s] = *(const bfrag*)(xl + a1 + s * 1024);
    }
  }
  __syncthreads();

#define LOADB(TL, BH, BL, SPD) { \
  const size_t bb_ = (size_t)((TL) * 8 + w) * 4096 + (size_t)lane * 16; \
  _Pragma("unroll") for (int s_ = 0; s_ < 4; ++s_) { \
    BH[s_] = *(const bfrag*)(xh + bb_ + s_ * 1024); \
    BL[s_] = *(const bfrag*)(xl + bb_ + s_ * 1024); } \
  SPD = sq[(TL) * 256 + w * 32 + col]; }

#define RESCAN { mv = -1.0f; mp = 0; \
  _Pragma("unroll") for (int c4_ = 0; c4_ < 8; ++c4_) { \
    float4 v4_ = *(const float4*)&topd[ownq * TSTR + c4_ * 4]; \
    if (v4_.x > mv) { mv = v4_.x; mp = c4_ * 4 + 0; } \
    if (v4_.y > mv) { mv = v4_.y; mp = c4_ * 4 + 1; } \
    if (v4_.z > mv) { mv = v4_.z; mp = c4_ * 4 + 2; } \
    if (v4_.w > mv) { mv = v4_.w; mp = c4_ * 4 + 3; } } }

#define INSERT(FIXEDN) { \
  if (ownq >= 0) { \
    int n_ = ((FIXEDN) >= 0) ? (FIXEDN) : (int)qcnt[ownq]; \
    if (n_ > QCAP) n_ = QCAP; \
    for (int e_ = 0; e_ < n_; ++e_) { \
      float d_ = qds[ownq * QSTR + e_]; \
      if (ocnt < 32) { \
        topd[ownq * TSTR + ocnt] = d_; topi[ownq * TSTR + ocnt] = qis[ownq * QSTR + e_]; \
        ocnt++; \
        if (ocnt == 32) { RESCAN } \
      } else if (d_ < mv) { \
        topd[ownq * TSTR + mp] = d_; topi[ownq * TSTR + mp] = qis[ownq * QSTR + e_]; \
        RESCAN \
      } } \
    if ((FIXEDN) < 0 && n_ > 0) qcnt[ownq] = 0; \
    if (ocnt == 32) thrRow[ownq] = 0.5f * (sqqR - mv); \
  } }

  // candidate iff d2 < tau  <=>  acc > 0.5*(sqq - tau) + 0.5*sqp
#define PUSHQ(ACC, QG, TL, SPv) { \
  const float sph_ = 0.5f * (SPv); \
  _Pragma("unroll") for (int m_ = 0; m_ < 4; ++m_) { \
    const float4 th_ = *(const float4*)&thrRow[(QG) * 32 + m_ * 8 + h * 4]; \
    _Pragma("unroll") for (int b_ = 0; b_ < 4; ++b_) { \
      const float av_ = ACC[m_ * 4 + b_]; \
      const float tb_ = (b_ == 0) ? th_.x : (b_ == 1) ? th_.y : (b_ == 2) ? th_.z : th_.w; \
      if (av_ > tb_ + sph_) { \
        const int qq_ = (QG) * 32 + b_ + 8 * m_ + 4 * h; \
        const int p_ = (TL) * 256 + w * 32 + col; \
        if (!(selfT_ && p_ == qg0 + qq_)) { \
          const float d2_ = fmaxf(sqq_s[qq_] + (SPv)-2.0f * av_, 0.0f); \
          const unsigned sl_ = atomicAdd(&qcnt[qq_], 1u); \
          if (sl_ < (unsigned)QCAP) { \
            qds[qq_ * QSTR + sl_] = d2_; qis[qq_ * QSTR + sl_] = (unsigned short)p_; } \
        } } } } }

  // tile 0, waves 0-2: every (q,p) slot is unique (p in [0,96)) -> no atomics
#define PUSH0(ACC, QG, SPv) { \
  _Pragma("unroll") for (int m_ = 0; m_ < 4; ++m_) { \
    _Pragma("unroll") for (int b_ = 0; b_ < 4; ++b_) { \
      const float av_ = ACC[m_ * 4 + b_]; \
      const int qq_ = (QG) * 32 + b_ + 8 * m_ + 4 * h; \
      const int p_ = w * 32 + col; \
      float d2_ = fmaxf(sqq_s[qq_] + (SPv)-2.0f * av_, 0.0f); \
      if (selfT_ && p_ == qg0 + qq_) d2_ = 1e30f; \
      qds[qq_ * QSTR + p_] = d2_; qis[qq_ * QSTR + p_] = (unsigned short)p_; } } }

#define BODY(TL, BH, BL, SPC, NBH, NBL, NSPC) { \
  const int tl_ = (TL); \
  if (tl_ + 1 < 64) LOADB(tl_ + 1, NBH, NBL, NSPC); \
  f32x16 a0, a1; \
  _Pragma("unroll") for (int i_ = 0; i_ < 16; ++i_) { a0[i_] = 0.f; a1[i_] = 0.f; } \
  _Pragma("unroll") for (int s_ = 0; s_ < 4; ++s_) { \
    a0 = __builtin_amdgcn_mfma_f32_32x32x16_bf16(ahi0[s_], BH[s_], a0, 0, 0, 0); \
    a1 = __builtin_amdgcn_mfma_f32_32x32x16_bf16(ahi1[s_], BH[s_], a1, 0, 0, 0); } \
  _Pragma("unroll") for (int s_ = 0; s_ < 4; ++s_) { \
    a0 = __builtin_amdgcn_mfma_f32_32x32x16_bf16(ahi0[s_], BL[s_], a0, 0, 0, 0); \
    a1 = __builtin_amdgcn_mfma_f32_32x32x16_bf16(ahi1[s_], BL[s_], a1, 0, 0, 0); } \
  _Pragma("unroll") for (int s_ = 0; s_ < 4; ++s_) { \
    a0 = __builtin_amdgcn_mfma_f32_32x32x16_bf16(alo0[s_], BH[s_], a0, 0, 0, 0); \
    a1 = __builtin_amdgcn_mfma_f32_32x32x16_bf16(alo1[s_], BH[s_], a1, 0, 0, 0); } \
  const bool selfT_ = (tl_ == selfTileIdx); \
  if (tl_ == 0) { \
    if (w < 3) { PUSH0(a0, 0, SPC) PUSH0(a1, 1, SPC) } \
    __syncthreads(); INSERT(96) __syncthreads(); \
    if (w >= 3 && w < 6) { PUSHQ(a0, 0, tl_, SPC) PUSHQ(a1, 1, tl_, SPC) } \
    __syncthreads(); INSERT(-1) __syncthreads(); \
    if (w >= 6) { PUSHQ(a0, 0, tl_, SPC) PUSHQ(a1, 1, tl_, SPC) } \
    __syncthreads(); INSERT(-1) __syncthreads(); \
  } else { \
    PUSHQ(a0, 0, tl_, SPC) PUSHQ(a1, 1, tl_, SPC) \
    __syncthreads(); INSERT(-1) __syncthreads(); \
  } }

  bfrag bh0[4], bl0[4], bh1[4], bl1[4];
  float sp0v = 0.f, sp1v = 0.f;
  LOADB(0, bh0, bl0, sp0v);
  for (int tp = 0; tp < 64; tp += 2) {
    BODY(tp, bh0, bl0, sp0v, bh1, bl1, sp1v);
    BODY(tp + 1, bh1, bl1, sp1v, bh0, bl0, sp0v);
  }

  // finalize: d=sqrt(d2), softmax(-2d) over the 32 slots (order-invariant)
  {
    const int qq = t >> 3, sl = t & 7;
    float d[4]; int id[4];
    float mn = 1e30f;
#pragma unroll
    for (int u = 0; u < 4; ++u) {
      const int k2 = sl * 4 + u;
      d[u] = sqrtf(topd[qq * TSTR + k2]);
      id[u] = (int)topi[qq * TSTR + k2];
      mn = fminf(mn, d[u]);
    }
#pragma unroll
    for (int m = 1; m < 8; m <<= 1) mn = fminf(mn, __shfl_xor(mn, m));
    float e[4], s2 = 0.f;
#pragma unroll
    for (int u = 0; u < 4; ++u) { e[u] = __expf((mn - d[u]) * 2.0f); s2 += e[u]; }
#pragma unroll
    for (int m = 1; m < 8; m <<= 1) s2 += __shfl_xor(s2, m);
    const float inv = 1.0f / s2;
#pragma unroll
    for (int u = 0; u < 4; ++u) {
      const int o = (qg0 + qq) * Kk + sl * 4 + u;
      nw[o] = e[u] * inv;
      nidx[o] = (unsigned short)id[u];
    }
  }
#undef LOADB
#undef RESCAN
#undef INSERT
#undef PUSHQ
#undef PUSH0
#undef BODY
}

// ---------------- one message-pass step, fused: gather+MLP+LN ----------------
#define RB 32
#define US 36

__global__ __launch_bounds__(256) void k_step(const float* __restrict__ x,
    const float* __restrict__ hin, const unsigned short* __restrict__ nidx,
    const float* __restrict__ nw, const float* __restrict__ Wm1,
    const float* __restrict__ bm1, const float* __restrict__ Wm2,
    const float* __restrict__ bm2, const float* __restrict__ g,
    const float* __restrict__ be, float* __restrict__ hout) {
  __shared__ float updT[2 * Hd + Fd][US];  // upd_in transposed: 320 x 36 (46 KB)
  __shared__ float t1T[Hd][US];            // silu(GEMM1) transposed (18 KB)
  const int t = threadIdx.x;
  const int r0 = blockIdx.x * RB;

  { // stage: hidden | agg (gather) | x, all transposed
    const int r = t >> 3, s = t & 7;
    const int i = r0 + r;
    const float* hr = hin + (size_t)i * Hd + (s << 4);
#pragma unroll
    for (int u = 0; u < 4; ++u) {
      float4 v = *(const float4*)(hr + (u << 2));
      const int c = (s << 4) + (u << 2);
      updT[c + 0][r] = v.x; updT[c + 1][r] = v.y;
      updT[c + 2][r] = v.z; updT[c + 3][r] = v.w;
    }
    float a[16];
#pragma unroll
    for (int u = 0; u < 16; ++u) a[u] = 0.f;
    const unsigned short* ir = nidx + i * Kk;
    const float* wr = nw + i * Kk;
    for (int k = 0; k < Kk; ++k) {
      const float wk = wr[k];
      const float* hv = hin + (size_t)ir[k] * Hd + (s << 4);
#pragma unroll
      for (int u = 0; u < 4; ++u) {
        float4 v = *(const float4*)(hv + (u << 2));
        a[(u << 2) + 0] = fmaf(wk, v.x, a[(u << 2) + 0]);
        a[(u << 2) + 1] = fmaf(wk, v.y, a[(u << 2) + 1]);
        a[(u << 2) + 2] = fmaf(wk, v.z, a[(u << 2) + 2]);
        a[(u << 2) + 3] = fmaf(wk, v.w, a[(u << 2) + 3]);
      }
    }
#pragma unroll
    for (int u = 0; u < 16; ++u) updT[Hd + (s << 4) + u][r] = a[u];
    const float* xr = x + (size_t)i * Fd + (s << 3);
    float4 x0 = *(const float4*)(xr);
    float4 x1 = *(const float4*)(xr + 4);
    const int c = 2 * Hd + (s << 3);
    updT[c + 0][r] = x0.x; updT[c + 1][r] = x0.y;
    updT[c + 2][r] = x0.z; updT[c + 3][r] = x0.w;
    updT[c + 4][r] = x1.x; updT[c + 5][r] = x1.y;
    updT[c + 6][r] = x1.z; updT[c + 7][r] = x1.w;
  }
  __syncthreads();

  const int rg = t >> 5, cg = t & 31;
  const int rr = rg << 2, cc = cg << 2;
  { // GEMM1 [32x320]x[320x128] + silu -> t1T
    float acc[4][4] = {};
#pragma unroll 4
    for (int k = 0; k < 2 * Hd + Fd; ++k) {
      float4 uv = *(const float4*)&updT[k][rr];
      float4 wv = *(const float4*)&Wm1[k * Hd + cc];
      FMA16(acc, uv, wv)
    }
    float4 b1 = *(const float4*)&bm1[cc];
    float bb1[4] = {b1.x, b1.y, b1.z, b1.w};
#pragma unroll
    for (int a = 0; a < 4; ++a)
#pragma unroll
      for (int b = 0; b < 4; ++b) {
        const float z = acc[a][b] + bb1[b];
        t1T[cc + b][rr + a] = z / (1.0f + __expf(-z));
      }
  }
  __syncthreads();
  { // GEMM2 [32x128]x[128x128] + residual + LayerNorm
    float acc[4][4] = {};
#pragma unroll 4
    for (int k = 0; k < Hd; ++k) {
      float4 uv = *(const float4*)&t1T[k][rr];
      float4 wv = *(const float4*)&Wm2[k * Hd + cc];
      FMA16(acc, uv, wv)
    }
    float4 b2 = *(const float4*)&bm2[cc];
    float bb2[4] = {b2.x, b2.y, b2.z, b2.w};
    float v[4][4];
#pragma unroll
    for (int b = 0; b < 4; ++b) {
      float4 hres = *(const float4*)&updT[cc + b][rr];  // residual = staged hidden
      v[0][b] = hres.x + acc[0][b] + bb2[b];
      v[1][b] = hres.y + acc[1][b] + bb2[b];
      v[2][b] = hres.z + acc[2][b] + bb2[b];
      v[3][b] = hres.w + acc[3][b] + bb2[b];
    }
    float4 gv = *(const float4*)&g[cc];
    float4 bev = *(const float4*)&be[cc];
    float gg[4] = {gv.x, gv.y, gv.z, gv.w};
    float eb[4] = {bev.x, bev.y, bev.z, bev.w};
#pragma unroll
    for (int a = 0; a < 4; ++a) {
      float sm = v[a][0] + v[a][1] + v[a][2] + v[a][3];
      float s2 = 0.f;
#pragma unroll
      for (int b = 0; b < 4; ++b) s2 = fmaf(v[a][b], v[a][b], s2);
#pragma unroll
      for (int m = 1; m < 32; m <<= 1) {
        sm += __shfl_xor(sm, m);
        s2 += __shfl_xor(s2, m);
      }
      const float mean = sm * (1.0f / 128.0f);
      const float var = fmaxf(s2 * (1.0f / 128.0f) - mean * mean, 0.0f);
      const float rstd = rsqrtf(var + 1e-5f);
      float4 o;
      o.x = (v[a][0] - mean) * rstd * gg[0] + eb[0];
      o.y = (v[a][1] - mean) * rstd * gg[1] + eb[1];
      o.z = (v[a][2] - mean) * rstd * gg[2] + eb[2];
      o.w = (v[a][3] - mean) * rstd * gg[3] + eb[3];
      *(float4*)&hout[(size_t)(r0 + rr + a) * Hd + cc] = o;
    }
  }
}

// ---------------- readout: softplus(silu([h,x]@Wr1+b)@Wr2+b) ----------------
__global__ __launch_bounds__(256) void k_out(const float* __restrict__ x,
    const float* __restrict__ hin, const float* __restrict__ Wr1,
    const float* __restrict__ br1, const float* __restrict__ Wr2,
    const float* __restrict__ br2, float* __restrict__ out) {
  __shared__ float rT[Hd + Fd][US];  // 192 x 36 (27 KB)
  const int t = threadIdx.x;
  const int r0 = blockIdx.x * RB;
  {
    const int r = t >> 3, s = t & 7;
    const int i = r0 + r;
    const float* hr = hin + (size_t)i * Hd + (s << 4);
#pragma unroll
    for (int u = 0; u < 4; ++u) {
      float4 v = *(const float4*)(hr + (u << 2));
      const int c = (s << 4) + (u << 2);
      rT[c + 0][r] = v.x; rT[c + 1][r] = v.y;
      rT[c + 2][r] = v.z; rT[c + 3][r] = v.w;
    }
    const float* xr = x + (size_t)i * Fd + (s << 3);
    float4 x0 = *(const float4*)(xr);
    float4 x1 = *(const float4*)(xr + 4);
    const int c = Hd + (s << 3);
    rT[c + 0][r] = x0.x; rT[c + 1][r] = x0.y;
    rT[c + 2][r] = x0.z; rT[c + 3][r] = x0.w;
    rT[c + 4][r] = x1.x; rT[c + 5][r] = x1.y;
    rT[c + 6][r] = x1.z; rT[c + 7][r] = x1.w;
  }
  __syncthreads();
  const int rg = t >> 5, cg = t & 31;
  const int rr = rg << 2, cc = cg << 2;
  float acc[4][4] = {};
#pragma unroll 4
  for (int k = 0; k < Hd + Fd; ++k) {
    float4 uv = *(const float4*)&rT[k][rr];
    float4 wv = *(const float4*)&Wr1[k * Hd + cc];
    FMA16(acc, uv, wv)
  }
  float4 b1 = *(const float4*)&br1[cc];
  float bb1[4] = {b1.x, b1.y, b1.z, b1.w};
  float4 w2 = *(const float4*)&Wr2[cc];
  float ww[4] = {w2.x, w2.y, w2.z, w2.w};
  float part[4];
#pragma unroll
  for (int a = 0; a < 4; ++a) {
    part[a] = 0.f;
#pragma unroll
    for (int b = 0; b < 4; ++b) {
      const float z = acc[a][b] + bb1[b];
      const float sil = z / (1.0f + __expf(-z));
      part[a] = fmaf(sil, ww[b], part[a]);
    }
  }
#pragma unroll
  for (int m = 1; m < 32; m <<= 1) {
#pragma unroll
    for (int a = 0; a < 4; ++a) part[a] += __shfl_xor(part[a], m);
  }
  if (cg == 0) {
    const float bias = br2[0];
#pragma unroll
    for (int a = 0; a < 4; ++a) {
      const float rv = part[a] + bias;
      out[r0 + rr + a] = fmaxf(rv, 0.0f) + log1pf(__expf(-fabsf(rv)));
    }
  }
}

extern "C" void kernel_launch(void* const* d_in, const int* in_sizes, int n_in,
                              void* d_out, int out_size, void* d_ws, size_t ws_size,
                              hipStream_t stream) {
  const float* x    = (const float*)d_in[0];
  const float* W_in = (const float*)d_in[1];
  const float* b_in = (const float*)d_in[2];
  const float* W_m1 = (const float*)d_in[3];
  const float* b_m1 = (const float*)d_in[4];
  const float* W_m2 = (const float*)d_in[5];
  const float* b_m2 = (const float*)d_in[6];
  const float* ln_g = (const float*)d_in[7];
  const float* ln_b = (const float*)d_in[8];
  const float* W_r1 = (const float*)d_in[9];
  const float* b_r1 = (const float*)d_in[10];
  const float* W_r2 = (const float*)d_in[11];
  const float* b_r2 = (const float*)d_in[12];
  float* out = (float*)d_out;

  char* ws = (char*)d_ws;
  const size_t MB = (size_t)1 << 20;
  float*          hidA = (float*)(ws);                 // 8 MB
  float*          hidB = (float*)(ws + 8 * MB);        // 8 MB
  short*          xbhi = (short*)(ws + 16 * MB);       // 2 MB
  short*          xblo = (short*)(ws + 18 * MB);       // 2 MB
  unsigned short* nidx = (unsigned short*)(ws + 20 * MB);  // 1 MB
  float*          nw   = (float*)(ws + 21 * MB);       // 2 MB
  float*          sq   = (float*)(ws + 23 * MB);       // 64 KB

  k_input<<<dim3(Nn / 2), dim3(256), 0, stream>>>(x, W_in, b_in, hidA, sq);
  k_prep<<<dim3(Nn * 8 / 256), dim3(256), 0, stream>>>(x, xbhi, xblo);
  k_knn<<<dim3(Nn / 64), dim3(512), 0, stream>>>(xbhi, xblo, sq, nidx, nw);
  k_step<<<dim3(Nn / RB), dim3(256), 0, stream>>>(x, hidA, nidx, nw, W_m1, b_m1,
                                                  W_m2, b_m2, ln_g, ln_b, hidB);
  k_step<<<dim3(Nn / RB), dim3(256), 0, stream>>>(x, hidB, nidx, nw, W_m1, b_m1,
                                                  W_m2, b_m2, ln_g, ln_b, hidA);
  k_out<<<dim3(Nn / RB), dim3(256), 0, stream>>>(x, hidA, W_r1, b_r1, W_r2, b_r2, out);
}